// Round 1
// baseline (271.489 us; speedup 1.0000x reference)
//
#include <hip/hip_runtime.h>
#include <hip/hip_bf16.h>
#include <stdint.h>

// Problem constants (fixed by setup_inputs)
#define N_NODES 16384   // B*H*W
#define NPB     4096    // nodes per batch (H*W)
#define NB      4
#define KNN     4
#define NEDGE   (N_NODES * 5)   // 4 kNN + 1 self loop per node

// ---------------- 64-bit wave shuffle helper ----------------
__device__ __forceinline__ unsigned long long shfl_xor_u64(unsigned long long v, int m) {
  unsigned lo = (unsigned)(v & 0xffffffffull);
  unsigned hi = (unsigned)(v >> 32);
  lo = __shfl_xor(lo, m, 64);
  hi = __shfl_xor(hi, m, 64);
  return (((unsigned long long)hi) << 32) | lo;
}

// ---------------- deg init ----------------
__global__ void init_deg_kernel(int* __restrict__ deg) {
  int i = blockIdx.x * 256 + threadIdx.x;
  if (i < N_NODES) deg[i] = 1;   // self loop
}

// ---------------- kNN: one wave per node ----------------
// Stable-argsort semantics: sort by (dist, idx) lexicographic, take positions 1..4.
__global__ void knn_kernel(const float* __restrict__ dm, int* __restrict__ tgt,
                           int* __restrict__ deg) {
  __shared__ float ds[NPB];
  int b = blockIdx.x >> 10;                 // 1024 blocks per batch
  const float* d = dm + b * NPB;
  for (int t = threadIdx.x; t < NPB; t += 256) ds[t] = d[t];
  __syncthreads();
  int wave = threadIdx.x >> 6;
  int lane = threadIdx.x & 63;
  int li = ((blockIdx.x & 1023) << 2) + wave;   // local node index in [0,4096)
  float di = ds[li];
  unsigned long long k0 = ~0ull, k1 = ~0ull, k2 = ~0ull, k3 = ~0ull, k4 = ~0ull;
  for (int t = 0; t < NPB / 64; ++t) {
    int j = (t << 6) + lane;
    float dist = fabsf(di - ds[j]);
    unsigned long long key = (((unsigned long long)__float_as_uint(dist)) << 32) | (unsigned)j;
    if (key < k4) {
      if (key < k0)      { k4 = k3; k3 = k2; k2 = k1; k1 = k0; k0 = key; }
      else if (key < k1) { k4 = k3; k3 = k2; k2 = k1; k1 = key; }
      else if (key < k2) { k4 = k3; k3 = k2; k2 = key; }
      else if (key < k3) { k4 = k3; k3 = key; }
      else               { k4 = key; }
    }
  }
  // 5 rounds of wave-min + pop; keys are unique (idx in low bits)
  int nbr[KNN];
  for (int r = 0; r < 5; ++r) {
    unsigned long long m = k0;
#pragma unroll
    for (int s = 32; s >= 1; s >>= 1) {
      unsigned long long o = shfl_xor_u64(m, s);
      if (o < m) m = o;
    }
    if (r >= 1) nbr[r - 1] = (int)(m & 0xffffffffull);
    if (k0 == m) { k0 = k1; k1 = k2; k2 = k3; k3 = k4; k4 = ~0ull; }
  }
  int node = b * NPB + li;
  if (lane < KNN) {
    int t = b * NPB + nbr[lane];
    tgt[node * KNN + lane] = t;
    atomicAdd(&deg[t], 1);
  }
}

// ---------------- dinv + exclusive scan (single block) ----------------
__global__ void scan_kernel(const int* __restrict__ deg, float* __restrict__ dinv,
                            int* __restrict__ off, int* __restrict__ cur) {
  __shared__ int part[256];
  int t = threadIdx.x;
  int base = t * 64;
  int s = 0;
  for (int i = 0; i < 64; ++i) s += deg[base + i];
  part[t] = s;
  __syncthreads();
  if (t == 0) {
    int acc = 0;
    for (int i = 0; i < 256; ++i) { int v = part[i]; part[i] = acc; acc += v; }
  }
  __syncthreads();
  int acc = part[t];
  for (int i = 0; i < 64; ++i) {
    int dg = deg[base + i];
    off[base + i] = acc;
    cur[base + i] = acc;
    dinv[base + i] = rsqrtf((float)dg);
    acc += dg;
  }
  if (t == 255) off[N_NODES] = acc;  // == NEDGE
}

// ---------------- CSR fill (incoming edges per node) ----------------
__global__ void fill_csr_kernel(const int* __restrict__ tgt, int* __restrict__ cur,
                                int* __restrict__ srcs) {
  int e = blockIdx.x * 256 + threadIdx.x;
  if (e >= NEDGE) return;
  int j = e / 5, q = e - j * 5;
  int target = (q < KNN) ? tgt[j * KNN + q] : j;   // q==4 -> self loop
  int pos = atomicAdd(&cur[target], 1);
  srcs[pos] = j;
}

// ---------------- generic batched 2D transpose: [B][Rin][Cin] -> [B][Cin][Rin] ----
__global__ void transpose_kernel(const float* __restrict__ in, float* __restrict__ out,
                                 int Rin, int Cin) {
  __shared__ float tile[32][33];
  int c0 = blockIdx.x * 32, r0 = blockIdx.y * 32, b = blockIdx.z;
  int tx = threadIdx.x & 31, ty = threadIdx.x >> 5;   // 32x8
  const float* ip = in + ((size_t)b * Rin + r0) * Cin + c0;
#pragma unroll
  for (int i = 0; i < 32; i += 8) tile[ty + i][tx] = ip[(size_t)(ty + i) * Cin + tx];
  __syncthreads();
  float* op = out + ((size_t)b * Cin + c0) * Rin + r0;
#pragma unroll
  for (int i = 0; i < 32; i += 8) op[(size_t)(ty + i) * Rin + tx] = tile[tx][ty + i];
}

// ---------------- graph propagate: out[i,:] = dinv[i]*sum_j dinv[j]*in[j,:] ------
template <bool BIAS_RELU>
__global__ void prop_kernel(const float* __restrict__ in, float* __restrict__ out,
                            const int* __restrict__ off, const int* __restrict__ srcs,
                            const float* __restrict__ dinv, const float* __restrict__ bias) {
  const int C = 256;
  int i = blockIdx.x;
  int c = threadIdx.x;
  int e0 = off[i], e1 = off[i + 1];
  float acc = 0.f;
  for (int e = e0; e < e1; ++e) {
    int j = srcs[e];
    acc += dinv[j] * in[(size_t)j * C + c];
  }
  acc *= dinv[i];
  if (BIAS_RELU) acc = fmaxf(acc + bias[c], 0.f);
  out[(size_t)i * C + c] = acc;
}

// ---------------- fp32 GEMM: C[M,N] = A[M,K] @ B[K,N] (+bias, relu) -------------
// 128x128 tile, BK=16, 256 threads, 8x8 micro-tile (split 4+4 fragments).
template <bool BIAS_RELU>
__global__ __launch_bounds__(256)
void gemm_kernel(const float* __restrict__ A, const float* __restrict__ B,
                 float* __restrict__ C, const float* __restrict__ bias,
                 int M, int N, int K) {
  __shared__ float As[16][128];
  __shared__ float Bs[16][128];
  int bm = blockIdx.x * 128;
  int bn = blockIdx.y * 128;
  int tid = threadIdx.x;
  int tx = tid & 15, ty = tid >> 4;
  float acc[8][8] = {};
  for (int k0 = 0; k0 < K; k0 += 16) {
    // A tile 128x16 -> As[k][m]
    {
      int r = tid >> 2;      // 0..63
      int q = tid & 3;       // float4 slot within 16 k's
      float4 v0 = *((const float4*)(A + (size_t)(bm + r) * K + k0) + q);
      float4 v1 = *((const float4*)(A + (size_t)(bm + r + 64) * K + k0) + q);
      As[q * 4 + 0][r] = v0.x; As[q * 4 + 1][r] = v0.y;
      As[q * 4 + 2][r] = v0.z; As[q * 4 + 3][r] = v0.w;
      As[q * 4 + 0][r + 64] = v1.x; As[q * 4 + 1][r + 64] = v1.y;
      As[q * 4 + 2][r + 64] = v1.z; As[q * 4 + 3][r + 64] = v1.w;
    }
    // B tile 16x128 -> Bs[k][n]
    {
      int row = tid >> 5;    // 0..7
      int c4 = tid & 31;
      *(float4*)&Bs[row][c4 * 4] =
          *(const float4*)(B + (size_t)(k0 + row) * N + bn + c4 * 4);
      *(float4*)&Bs[row + 8][c4 * 4] =
          *(const float4*)(B + (size_t)(k0 + row + 8) * N + bn + c4 * 4);
    }
    __syncthreads();
#pragma unroll
    for (int k = 0; k < 16; ++k) {
      float a[8], b[8];
      *(float4*)(a + 0) = *(float4*)&As[k][ty * 4];
      *(float4*)(a + 4) = *(float4*)&As[k][64 + ty * 4];
      *(float4*)(b + 0) = *(float4*)&Bs[k][tx * 4];
      *(float4*)(b + 4) = *(float4*)&Bs[k][64 + tx * 4];
#pragma unroll
      for (int i = 0; i < 8; ++i)
#pragma unroll
        for (int j = 0; j < 8; ++j) acc[i][j] += a[i] * b[j];
    }
    __syncthreads();
  }
  // write back
#pragma unroll
  for (int i = 0; i < 8; ++i) {
    int r = bm + ((i < 4) ? (ty * 4 + i) : (64 + ty * 4 + (i - 4)));
    int c0 = bn + tx * 4, c1 = bn + 64 + tx * 4;
    float o[8];
#pragma unroll
    for (int j = 0; j < 8; ++j) o[j] = acc[i][j];
    if (BIAS_RELU) {
#pragma unroll
      for (int j = 0; j < 4; ++j) o[j] = fmaxf(o[j] + bias[c0 + j], 0.f);
#pragma unroll
      for (int j = 4; j < 8; ++j) o[j] = fmaxf(o[j] + bias[c1 + j - 4], 0.f);
    }
    *(float4*)(C + (size_t)r * N + c0) = *(float4*)(o + 0);
    *(float4*)(C + (size_t)r * N + c1) = *(float4*)(o + 4);
  }
}

// ---------------- launch ----------------
extern "C" void kernel_launch(void* const* d_in, const int* in_sizes, int n_in,
                              void* d_out, int out_size, void* d_ws, size_t ws_size,
                              hipStream_t stream) {
  const float* dm = (const float*)d_in[0];   // [4,1,64,64]
  const float* fm = (const float*)d_in[1];   // [4,256,64,64]
  const float* W1 = (const float*)d_in[2];   // [256,512]
  const float* b1 = (const float*)d_in[3];   // [512]
  const float* W2 = (const float*)d_in[4];   // [512,256]
  const float* b2 = (const float*)d_in[5];   // [256]
  float* out = (float*)d_out;                // [4,256,64,64]

  char* ws = (char*)d_ws;
  int*   tgt  = (int*)(ws + 0x00000);           // 256KB
  int*   deg  = (int*)(ws + 0x40000);           // 64KB
  float* dinv = (float*)(ws + 0x50000);         // 64KB
  int*   off  = (int*)(ws + 0x60000);           // 64KB+4
  int*   cur  = (int*)(ws + 0x80000);           // 64KB+4
  int*   srcs = (int*)(ws + 0xA0000);           // 320KB
  float* bufA = (float*)(ws + 0x0100000);       // 16MB: x_nm / o_nm
  float* bufB = (float*)(ws + 0x1100000);       // 16MB: px / t2
  float* bufC = (float*)(ws + 0x2100000);       // 32MB: h1
  // total ≈ 65MB; assume ws_size is sufficient
  (void)ws_size; (void)in_sizes; (void)n_in; (void)out_size;

  init_deg_kernel<<<64, 256, 0, stream>>>(deg);
  knn_kernel<<<4096, 256, 0, stream>>>(dm, tgt, deg);
  scan_kernel<<<1, 256, 0, stream>>>(deg, dinv, off, cur);
  fill_csr_kernel<<<NEDGE / 256, 256, 0, stream>>>(tgt, cur, srcs);

  // feature maps [B][256][4096] -> node-major [B][4096][256]
  transpose_kernel<<<dim3(4096 / 32, 256 / 32, NB), 256, 0, stream>>>(fm, bufA, 256, 4096);

  // layer 1: propagate x (256) then GEMM -> relu(.@W1 + b1)
  prop_kernel<false><<<N_NODES, 256, 0, stream>>>(bufA, bufB, off, srcs, dinv, nullptr);
  gemm_kernel<true><<<dim3(16384 / 128, 512 / 128), 256, 0, stream>>>(
      bufB, W1, bufC, b1, 16384, 512, 256);

  // layer 2: GEMM (h1@W2) then propagate + bias + relu
  gemm_kernel<false><<<dim3(16384 / 128, 256 / 128), 256, 0, stream>>>(
      bufC, W2, bufB, nullptr, 16384, 256, 512);
  prop_kernel<true><<<N_NODES, 256, 0, stream>>>(bufB, bufA, off, srcs, dinv, b2);

  // node-major [B][4096][256] -> [B][256][4096]
  transpose_kernel<<<dim3(256 / 32, 4096 / 32, NB), 256, 0, stream>>>(bufA, out, 4096, 256);
}

// Round 3
// 161.631 us; speedup vs baseline: 1.6797x; 1.6797x over previous
//
#include <hip/hip_runtime.h>
#include <hip/hip_bf16.h>
#include <stdint.h>

// Problem constants (fixed by setup_inputs)
#define N_NODES 16384   // B*H*W
#define NPB     4096    // nodes per batch (H*W)
#define NB      4
#define KNN     4
#define NEDGE   (N_NODES * 5)   // 4 kNN + 1 self loop per node

typedef short bf16x8 __attribute__((ext_vector_type(8)));
typedef float f32x4 __attribute__((ext_vector_type(4)));

__device__ __forceinline__ unsigned short f2bf(float f) {
  unsigned u = __float_as_uint(f);
  unsigned r = (u + 0x7fff + ((u >> 16) & 1)) >> 16;   // RNE
  return (unsigned short)r;
}

// ---------------- 64-bit wave shuffle helper ----------------
__device__ __forceinline__ unsigned long long shfl_xor_u64(unsigned long long v, int m) {
  unsigned lo = (unsigned)(v & 0xffffffffull);
  unsigned hi = (unsigned)(v >> 32);
  lo = __shfl_xor(lo, m, 64);
  hi = __shfl_xor(hi, m, 64);
  return (((unsigned long long)hi) << 32) | lo;
}

// ---------------- deg init ----------------
__global__ void init_deg_kernel(int* __restrict__ deg) {
  int i = blockIdx.x * 256 + threadIdx.x;
  if (i < N_NODES) deg[i] = 1;   // self loop
}

// ---------------- kNN: one wave per node ----------------
// Stable-argsort semantics: sort by (dist, idx) lexicographic, take positions 1..4.
__global__ void knn_kernel(const float* __restrict__ dm, int* __restrict__ tgt,
                           int* __restrict__ deg) {
  __shared__ float ds[NPB];
  int b = blockIdx.x >> 10;                 // 1024 blocks per batch
  const float* d = dm + b * NPB;
  for (int t = threadIdx.x; t < NPB; t += 256) ds[t] = d[t];
  __syncthreads();
  int wave = threadIdx.x >> 6;
  int lane = threadIdx.x & 63;
  int li = ((blockIdx.x & 1023) << 2) + wave;   // local node index in [0,4096)
  float di = ds[li];
  unsigned long long k0 = ~0ull, k1 = ~0ull, k2 = ~0ull, k3 = ~0ull, k4 = ~0ull;
  for (int t = 0; t < NPB / 64; ++t) {
    int j = (t << 6) + lane;
    float dist = fabsf(di - ds[j]);
    unsigned long long key = (((unsigned long long)__float_as_uint(dist)) << 32) | (unsigned)j;
    if (key < k4) {
      if (key < k0)      { k4 = k3; k3 = k2; k2 = k1; k1 = k0; k0 = key; }
      else if (key < k1) { k4 = k3; k3 = k2; k2 = k1; k1 = key; }
      else if (key < k2) { k4 = k3; k3 = k2; k2 = key; }
      else if (key < k3) { k4 = k3; k3 = key; }
      else               { k4 = key; }
    }
  }
  int nbr[KNN];
  for (int r = 0; r < 5; ++r) {
    unsigned long long m = k0;
#pragma unroll
    for (int s = 32; s >= 1; s >>= 1) {
      unsigned long long o = shfl_xor_u64(m, s);
      if (o < m) m = o;
    }
    if (r >= 1) nbr[r - 1] = (int)(m & 0xffffffffull);
    if (k0 == m) { k0 = k1; k1 = k2; k2 = k3; k3 = k4; k4 = ~0ull; }
  }
  int node = b * NPB + li;
  if (lane < KNN) {
    int t = b * NPB + nbr[lane];
    tgt[node * KNN + lane] = t;
    atomicAdd(&deg[t], 1);
  }
}

// ---------------- dinv + exclusive scan (single block) ----------------
__global__ void scan_kernel(const int* __restrict__ deg, float* __restrict__ dinv,
                            int* __restrict__ off, int* __restrict__ cur) {
  __shared__ int part[256];
  int t = threadIdx.x;
  int base = t * 64;
  int s = 0;
  for (int i = 0; i < 64; ++i) s += deg[base + i];
  part[t] = s;
  __syncthreads();
  if (t == 0) {
    int acc = 0;
    for (int i = 0; i < 256; ++i) { int v = part[i]; part[i] = acc; acc += v; }
  }
  __syncthreads();
  int acc = part[t];
  for (int i = 0; i < 64; ++i) {
    int dg = deg[base + i];
    off[base + i] = acc;
    cur[base + i] = acc;
    dinv[base + i] = rsqrtf((float)dg);
    acc += dg;
  }
  if (t == 255) off[N_NODES] = acc;  // == NEDGE
}

// ---------------- CSR fill (incoming edges per node) ----------------
__global__ void fill_csr_kernel(const int* __restrict__ tgt, int* __restrict__ cur,
                                int* __restrict__ srcs) {
  int e = blockIdx.x * 256 + threadIdx.x;
  if (e >= NEDGE) return;
  int j = e / 5, q = e - j * 5;
  int target = (q < KNN) ? tgt[j * KNN + q] : j;   // q==4 -> self loop
  int pos = atomicAdd(&cur[target], 1);
  srcs[pos] = j;
}

// ---------------- fp32 batched transpose: [B][Rin][Cin] -> [B][Cin][Rin] --------
__global__ void transpose_kernel(const float* __restrict__ in, float* __restrict__ out,
                                 int Rin, int Cin) {
  __shared__ float tile[32][33];
  int c0 = blockIdx.x * 32, r0 = blockIdx.y * 32, b = blockIdx.z;
  int tx = threadIdx.x & 31, ty = threadIdx.x >> 5;   // 32x8
  const float* ip = in + ((size_t)b * Rin + r0) * Cin + c0;
#pragma unroll
  for (int i = 0; i < 32; i += 8) tile[ty + i][tx] = ip[(size_t)(ty + i) * Cin + tx];
  __syncthreads();
  float* op = out + ((size_t)b * Cin + c0) * Rin + r0;
#pragma unroll
  for (int i = 0; i < 32; i += 8) op[(size_t)(ty + i) * Rin + tx] = tile[tx][ty + i];
}

// ---------------- transpose + fp32->bf16 convert (for weights) ------------------
__global__ void transpose_cvt_bf16_kernel(const float* __restrict__ in,
                                          unsigned short* __restrict__ out,
                                          int Rin, int Cin) {
  __shared__ float tile[32][33];
  int c0 = blockIdx.x * 32, r0 = blockIdx.y * 32;
  int tx = threadIdx.x & 31, ty = threadIdx.x >> 5;
  const float* ip = in + (size_t)r0 * Cin + c0;
#pragma unroll
  for (int i = 0; i < 32; i += 8) tile[ty + i][tx] = ip[(size_t)(ty + i) * Cin + tx];
  __syncthreads();
  unsigned short* op = out + (size_t)c0 * Rin + r0;
#pragma unroll
  for (int i = 0; i < 32; i += 8) op[(size_t)(ty + i) * Rin + tx] = f2bf(tile[tx][ty + i]);
}

// ---------------- graph propagate: out[i,:] = dinv[i]*sum_j dinv[j]*in[j,:] ------
// 4 nodes per block; lane handles 4 channels via float4.  C = 256 fixed.
template <bool OUT_BF16, bool BIAS_RELU>
__global__ void prop_kernel(const float* __restrict__ in, void* __restrict__ out,
                            const int* __restrict__ off, const int* __restrict__ srcs,
                            const float* __restrict__ dinv, const float* __restrict__ bias) {
  int i = blockIdx.x * 4 + (threadIdx.x >> 6);
  int l = threadIdx.x & 63;
  int e0 = off[i], e1 = off[i + 1];
  float ax = 0.f, ay = 0.f, az = 0.f, aw = 0.f;
  for (int e = e0; e < e1; ++e) {
    int j = srcs[e];
    float dj = dinv[j];
    float4 v = *(const float4*)(in + (size_t)j * 256 + l * 4);
    ax = fmaf(dj, v.x, ax); ay = fmaf(dj, v.y, ay);
    az = fmaf(dj, v.z, az); aw = fmaf(dj, v.w, aw);
  }
  float di = dinv[i];
  ax *= di; ay *= di; az *= di; aw *= di;
  if (BIAS_RELU) {
    ax = fmaxf(ax + bias[l * 4 + 0], 0.f);
    ay = fmaxf(ay + bias[l * 4 + 1], 0.f);
    az = fmaxf(az + bias[l * 4 + 2], 0.f);
    aw = fmaxf(aw + bias[l * 4 + 3], 0.f);
  }
  if (OUT_BF16) {
    ushort4 o;
    o.x = f2bf(ax); o.y = f2bf(ay); o.z = f2bf(az); o.w = f2bf(aw);
    *(ushort4*)((unsigned short*)out + (size_t)i * 256 + l * 4) = o;
  } else {
    float4 o = make_float4(ax, ay, az, aw);
    *(float4*)((float*)out + (size_t)i * 256 + l * 4) = o;
  }
}

// ---------------- bf16 MFMA GEMM: C[M,N] = A[M,K] @ Bt[N,K]^T (+bias, relu) -----
// 128x128 tile, BK=64, 4 waves (2x2 of 64x64), global_load_lds width 16,
// XOR-swizzled LDS (chunk ^= row&7) applied on the GLOBAL source (rule #21).
template <bool BIAS_RELU, bool OUT_BF16>
__global__ __launch_bounds__(256)
void gemm_bf16_kernel(const unsigned short* __restrict__ A,   // [M][K] bf16
                      const unsigned short* __restrict__ Bt,  // [N][K] bf16
                      void* __restrict__ C, const float* __restrict__ bias,
                      int M, int N, int K) {
  __shared__ char lds[32768];   // As[128][128B] then Bs[128][128B]
  const int tid = threadIdx.x;
  const int l = tid & 63, w = tid >> 6;
  const int bm = blockIdx.x * 128, bn = blockIdx.y * 128;
  const int wm = w >> 1, wn = w & 1;
  f32x4 acc[4][4] = {};

  for (int k0 = 0; k0 < K; k0 += 64) {
    __syncthreads();   // previous tile's reads complete before overwrite
    // stage A tile (rows bm..bm+127, k0..k0+63) and Bt tile, 16B/lane, swizzled src
#pragma unroll
    for (int q = 0; q < 4; ++q) {
      int o = q * 4096 + tid * 16;          // linear LDS byte offset
      int r = o >> 7;                        // tile row
      int pc = (o >> 4) & 7;                 // LDS chunk (16B units)
      int gc = pc ^ (r & 7);                 // global chunk to land here
      const char* srcA = (const char*)A + ((size_t)(bm + r) * K + k0) * 2 + gc * 16;
      const char* srcB = (const char*)Bt + ((size_t)(bn + r) * K + k0) * 2 + gc * 16;
      __builtin_amdgcn_global_load_lds(
          (const __attribute__((address_space(1))) void*)srcA,
          (__attribute__((address_space(3))) void*)(lds + o), 16, 0, 0);
      __builtin_amdgcn_global_load_lds(
          (const __attribute__((address_space(1))) void*)srcB,
          (__attribute__((address_space(3))) void*)(lds + 16384 + o), 16, 0, 0);
    }
    __syncthreads();   // compiler drains vmcnt(0) before barrier

#pragma unroll
    for (int kk = 0; kk < 64; kk += 32) {
      bf16x8 af[4], bf[4];
#pragma unroll
      for (int mi = 0; mi < 4; ++mi) {
        int r = wm * 64 + mi * 16 + (l & 15);
        int gc = (kk >> 3) + (l >> 4);
        af[mi] = *(const bf16x8*)(lds + r * 128 + ((gc ^ (r & 7)) << 4));
      }
#pragma unroll
      for (int ni = 0; ni < 4; ++ni) {
        int r = wn * 64 + ni * 16 + (l & 15);
        int gc = (kk >> 3) + (l >> 4);
        bf[ni] = *(const bf16x8*)(lds + 16384 + r * 128 + ((gc ^ (r & 7)) << 4));
      }
#pragma unroll
      for (int mi = 0; mi < 4; ++mi)
#pragma unroll
        for (int ni = 0; ni < 4; ++ni)
          acc[mi][ni] = __builtin_amdgcn_mfma_f32_16x16x32_bf16(af[mi], bf[ni],
                                                                acc[mi][ni], 0, 0, 0);
    }
  }

  // epilogue: C row = bm+wm*64+mi*16+(l>>4)*4+r, col = bn+wn*64+ni*16+(l&15)
#pragma unroll
  for (int mi = 0; mi < 4; ++mi) {
#pragma unroll
    for (int ni = 0; ni < 4; ++ni) {
      int row0 = bm + wm * 64 + mi * 16 + ((l >> 4) << 2);
      int col = bn + wn * 64 + ni * 16 + (l & 15);
      float bv = BIAS_RELU ? bias[col] : 0.f;
      f32x4 v = acc[mi][ni];
#pragma unroll
      for (int r = 0; r < 4; ++r) {
        float val = v[r];
        if (BIAS_RELU) val = fmaxf(val + bv, 0.f);
        if (OUT_BF16)
          ((unsigned short*)C)[(size_t)(row0 + r) * N + col] = f2bf(val);
        else
          ((float*)C)[(size_t)(row0 + r) * N + col] = val;
      }
    }
  }
}

// ---------------- launch ----------------
extern "C" void kernel_launch(void* const* d_in, const int* in_sizes, int n_in,
                              void* d_out, int out_size, void* d_ws, size_t ws_size,
                              hipStream_t stream) {
  const float* dm = (const float*)d_in[0];   // [4,1,64,64]
  const float* fm = (const float*)d_in[1];   // [4,256,64,64]
  const float* W1 = (const float*)d_in[2];   // [256,512]
  const float* b1 = (const float*)d_in[3];   // [512]
  const float* W2 = (const float*)d_in[4];   // [512,256]
  const float* b2 = (const float*)d_in[5];   // [256]
  float* out = (float*)d_out;                // [4,256,64,64]

  char* ws = (char*)d_ws;
  int*            tgt  = (int*)(ws + 0x000000);
  int*            deg  = (int*)(ws + 0x040000);
  float*          dinv = (float*)(ws + 0x050000);
  int*            off  = (int*)(ws + 0x060000);
  int*            cur  = (int*)(ws + 0x080000);
  int*            srcs = (int*)(ws + 0x0A0000);
  unsigned short* W1t  = (unsigned short*)(ws + 0x0F0000);   // [512][256] bf16
  unsigned short* W2t  = (unsigned short*)(ws + 0x130000);   // [256][512] bf16
  float*          x    = (float*)(ws + 0x200000);            // [16384][256] f32 (also o)
  unsigned short* px   = (unsigned short*)(ws + 0x1200000);  // [16384][256] bf16
  unsigned short* h1   = (unsigned short*)(ws + 0x1A00000);  // [16384][512] bf16
  float*          t2   = (float*)(ws + 0x2A00000);           // [16384][256] f32
  (void)ws_size; (void)in_sizes; (void)n_in; (void)out_size;

  init_deg_kernel<<<64, 256, 0, stream>>>(deg);
  knn_kernel<<<4096, 256, 0, stream>>>(dm, tgt, deg);
  scan_kernel<<<1, 256, 0, stream>>>(deg, dinv, off, cur);
  fill_csr_kernel<<<NEDGE / 256, 256, 0, stream>>>(tgt, cur, srcs);

  // weights -> bf16 [N][K]
  transpose_cvt_bf16_kernel<<<dim3(512 / 32, 256 / 32), 256, 0, stream>>>(W1, W1t, 256, 512);
  transpose_cvt_bf16_kernel<<<dim3(256 / 32, 512 / 32), 256, 0, stream>>>(W2, W2t, 512, 256);

  // feature maps [B][256][4096] -> node-major [B*4096][256]
  transpose_kernel<<<dim3(4096 / 32, 256 / 32, NB), 256, 0, stream>>>(fm, x, 256, 4096);

  // layer 1: propagate x (256) -> bf16, then MFMA GEMM relu(.@W1+b1) -> bf16
  prop_kernel<true, false><<<N_NODES / 4, 256, 0, stream>>>(x, px, off, srcs, dinv, nullptr);
  gemm_bf16_kernel<true, true><<<dim3(128, 4), 256, 0, stream>>>(
      px, W1t, h1, b1, 16384, 512, 256);

  // layer 2: MFMA GEMM h1@W2 -> f32, then propagate + bias + relu (f32, into x buf)
  gemm_bf16_kernel<false, false><<<dim3(128, 2), 256, 0, stream>>>(
      h1, W2t, t2, nullptr, 16384, 256, 512);
  prop_kernel<false, true><<<N_NODES / 4, 256, 0, stream>>>(t2, x, off, srcs, dinv, b2);

  // node-major -> [B][256][4096]
  transpose_kernel<<<dim3(256 / 32, 4096 / 32, NB), 256, 0, stream>>>(x, out, 4096, 256);
}

// Round 4
// 150.490 us; speedup vs baseline: 1.8040x; 1.0740x over previous
//
#include <hip/hip_runtime.h>
#include <hip/hip_bf16.h>
#include <stdint.h>

// Problem constants (fixed by setup_inputs)
#define N_NODES 16384   // B*H*W
#define NPB     4096    // nodes per batch (H*W)
#define NB      4
#define KNN     4
#define NEDGE   (N_NODES * 5)   // 4 kNN + 1 self loop per node
#define WIN     12      // sorted-order window radius for exact 1-D kNN

typedef short bf16x8 __attribute__((ext_vector_type(8)));
typedef float f32x4 __attribute__((ext_vector_type(4)));

__device__ __forceinline__ unsigned short f2bf(float f) {
  unsigned u = __float_as_uint(f);
  unsigned r = (u + 0x7fff + ((u >> 16) & 1)) >> 16;   // RNE
  return (unsigned short)r;
}

// ---------------- deg init ----------------
__global__ void init_deg_kernel(int* __restrict__ deg) {
  int i = blockIdx.x * 256 + threadIdx.x;
  if (i < N_NODES) deg[i] = 1;   // self loop
}

// ---------------- per-batch bitonic sort of (value,idx) u64 keys ----------------
// Density values are fp32 in [0,1) -> positive -> bit pattern is order-preserving.
// Key = (value_bits << 32) | local_idx ; unique keys, lexicographic (value, idx).
__global__ __launch_bounds__(1024)
void sort_kernel(const float* __restrict__ dm, unsigned long long* __restrict__ skeys,
                 int* __restrict__ rank) {
  __shared__ unsigned long long keys[NPB];   // 32 KB
  int b = blockIdx.x;
  const float* d = dm + b * NPB;
  for (int t = threadIdx.x; t < NPB; t += 1024)
    keys[t] = (((unsigned long long)__float_as_uint(d[t])) << 32) | (unsigned)t;
  __syncthreads();
  for (int k = 2; k <= NPB; k <<= 1) {
    for (int j = k >> 1; j > 0; j >>= 1) {
      for (int t = threadIdx.x; t < NPB / 2; t += 1024) {
        int i = ((t & ~(j - 1)) << 1) | (t & (j - 1));
        int p = i | j;
        bool up = ((i & k) == 0);
        unsigned long long a = keys[i], c = keys[p];
        if ((a > c) == up) { keys[i] = c; keys[p] = a; }
      }
      __syncthreads();
    }
  }
  for (int t = threadIdx.x; t < NPB; t += 1024) {
    unsigned long long kk = keys[t];
    skeys[b * NPB + t] = kk;
    rank[b * NPB + (int)(kk & 0xffffffffull)] = t;
  }
}

// ---------------- kNN select: exact top-5 by (dist,idx) within sorted window -----
__global__ void knn_select_kernel(const unsigned long long* __restrict__ skeys,
                                  const int* __restrict__ rank,
                                  int* __restrict__ tgt, int* __restrict__ deg) {
  int node = blockIdx.x * 256 + threadIdx.x;
  if (node >= N_NODES) return;
  int b = node >> 12;            // / NPB
  int p = rank[node];
  const unsigned long long* sk = skeys + b * NPB;
  float di = __uint_as_float((unsigned)(sk[p] >> 32));
  int lo = p - WIN; if (lo < 0) lo = 0;
  int hi = p + WIN; if (hi > NPB - 1) hi = NPB - 1;
  unsigned long long k0 = ~0ull, k1 = ~0ull, k2 = ~0ull, k3 = ~0ull, k4 = ~0ull;
  for (int q = lo; q <= hi; ++q) {
    unsigned long long key = sk[q];
    float v = __uint_as_float((unsigned)(key >> 32));
    float dist = fabsf(di - v);
    unsigned long long dk = (((unsigned long long)__float_as_uint(dist)) << 32) |
                            (key & 0xffffffffull);
    if (dk < k4) {
      if (dk < k0)      { k4 = k3; k3 = k2; k2 = k1; k1 = k0; k0 = dk; }
      else if (dk < k1) { k4 = k3; k3 = k2; k2 = k1; k1 = dk; }
      else if (dk < k2) { k4 = k3; k3 = k2; k2 = dk; }
      else if (dk < k3) { k4 = k3; k3 = dk; }
      else              { k4 = dk; }
    }
  }
  // conceptual argsort positions 0..4 = k0..k4 ; targets = positions 1..4
  int base = b * NPB;
  int t0 = base + (int)(k1 & 0xffffffffull);
  int t1 = base + (int)(k2 & 0xffffffffull);
  int t2 = base + (int)(k3 & 0xffffffffull);
  int t3 = base + (int)(k4 & 0xffffffffull);
  tgt[node * KNN + 0] = t0; atomicAdd(&deg[t0], 1);
  tgt[node * KNN + 1] = t1; atomicAdd(&deg[t1], 1);
  tgt[node * KNN + 2] = t2; atomicAdd(&deg[t2], 1);
  tgt[node * KNN + 3] = t3; atomicAdd(&deg[t3], 1);
}

// ---------------- dinv + exclusive scan (single block) ----------------
__global__ void scan_kernel(const int* __restrict__ deg, float* __restrict__ dinv,
                            int* __restrict__ off, int* __restrict__ cur) {
  __shared__ int part[256];
  int t = threadIdx.x;
  int base = t * 64;
  int s = 0;
  for (int i = 0; i < 64; ++i) s += deg[base + i];
  part[t] = s;
  __syncthreads();
  if (t == 0) {
    int acc = 0;
    for (int i = 0; i < 256; ++i) { int v = part[i]; part[i] = acc; acc += v; }
  }
  __syncthreads();
  int acc = part[t];
  for (int i = 0; i < 64; ++i) {
    int dg = deg[base + i];
    off[base + i] = acc;
    cur[base + i] = acc;
    dinv[base + i] = rsqrtf((float)dg);
    acc += dg;
  }
  if (t == 255) off[N_NODES] = acc;  // == NEDGE
}

// ---------------- CSR fill (incoming edges per node) ----------------
__global__ void fill_csr_kernel(const int* __restrict__ tgt, int* __restrict__ cur,
                                int* __restrict__ srcs) {
  int e = blockIdx.x * 256 + threadIdx.x;
  if (e >= NEDGE) return;
  int j = e / 5, q = e - j * 5;
  int target = (q < KNN) ? tgt[j * KNN + q] : j;   // q==4 -> self loop
  int pos = atomicAdd(&cur[target], 1);
  srcs[pos] = j;
}

// ---------------- fp32 batched transpose: [B][Rin][Cin] -> [B][Cin][Rin] --------
__global__ void transpose_kernel(const float* __restrict__ in, float* __restrict__ out,
                                 int Rin, int Cin) {
  __shared__ float tile[32][33];
  int c0 = blockIdx.x * 32, r0 = blockIdx.y * 32, b = blockIdx.z;
  int tx = threadIdx.x & 31, ty = threadIdx.x >> 5;   // 32x8
  const float* ip = in + ((size_t)b * Rin + r0) * Cin + c0;
#pragma unroll
  for (int i = 0; i < 32; i += 8) tile[ty + i][tx] = ip[(size_t)(ty + i) * Cin + tx];
  __syncthreads();
  float* op = out + ((size_t)b * Cin + c0) * Rin + r0;
#pragma unroll
  for (int i = 0; i < 32; i += 8) op[(size_t)(ty + i) * Rin + tx] = tile[tx][ty + i];
}

// ---------------- transpose + fp32->bf16 convert (for weights) ------------------
__global__ void transpose_cvt_bf16_kernel(const float* __restrict__ in,
                                          unsigned short* __restrict__ out,
                                          int Rin, int Cin) {
  __shared__ float tile[32][33];
  int c0 = blockIdx.x * 32, r0 = blockIdx.y * 32;
  int tx = threadIdx.x & 31, ty = threadIdx.x >> 5;
  const float* ip = in + (size_t)r0 * Cin + c0;
#pragma unroll
  for (int i = 0; i < 32; i += 8) tile[ty + i][tx] = ip[(size_t)(ty + i) * Cin + tx];
  __syncthreads();
  unsigned short* op = out + (size_t)c0 * Rin + r0;
#pragma unroll
  for (int i = 0; i < 32; i += 8) op[(size_t)(ty + i) * Rin + tx] = f2bf(tile[tx][ty + i]);
}

// ---------------- graph propagate: out[i,:] = dinv[i]*sum_j dinv[j]*in[j,:] ------
// 4 nodes per block; lane handles 4 channels via float4.  C = 256 fixed.
template <bool OUT_BF16, bool BIAS_RELU>
__global__ void prop_kernel(const float* __restrict__ in, void* __restrict__ out,
                            const int* __restrict__ off, const int* __restrict__ srcs,
                            const float* __restrict__ dinv, const float* __restrict__ bias) {
  int i = blockIdx.x * 4 + (threadIdx.x >> 6);
  int l = threadIdx.x & 63;
  int e0 = off[i], e1 = off[i + 1];
  float ax = 0.f, ay = 0.f, az = 0.f, aw = 0.f;
  for (int e = e0; e < e1; ++e) {
    int j = srcs[e];
    float dj = dinv[j];
    float4 v = *(const float4*)(in + (size_t)j * 256 + l * 4);
    ax = fmaf(dj, v.x, ax); ay = fmaf(dj, v.y, ay);
    az = fmaf(dj, v.z, az); aw = fmaf(dj, v.w, aw);
  }
  float di = dinv[i];
  ax *= di; ay *= di; az *= di; aw *= di;
  if (BIAS_RELU) {
    ax = fmaxf(ax + bias[l * 4 + 0], 0.f);
    ay = fmaxf(ay + bias[l * 4 + 1], 0.f);
    az = fmaxf(az + bias[l * 4 + 2], 0.f);
    aw = fmaxf(aw + bias[l * 4 + 3], 0.f);
  }
  if (OUT_BF16) {
    ushort4 o;
    o.x = f2bf(ax); o.y = f2bf(ay); o.z = f2bf(az); o.w = f2bf(aw);
    *(ushort4*)((unsigned short*)out + (size_t)i * 256 + l * 4) = o;
  } else {
    float4 o = make_float4(ax, ay, az, aw);
    *(float4*)((float*)out + (size_t)i * 256 + l * 4) = o;
  }
}

// ---------------- bf16 MFMA GEMM: C[M,N] = A[M,K] @ Bt[N,K]^T (+bias, relu) -----
// 128x128 tile, BK=64, 4 waves (2x2 of 64x64), global_load_lds width 16,
// XOR-swizzled LDS (chunk ^= row&7) applied on the GLOBAL source (rule #21).
template <bool BIAS_RELU, bool OUT_BF16>
__global__ __launch_bounds__(256)
void gemm_bf16_kernel(const unsigned short* __restrict__ A,   // [M][K] bf16
                      const unsigned short* __restrict__ Bt,  // [N][K] bf16
                      void* __restrict__ C, const float* __restrict__ bias,
                      int M, int N, int K) {
  __shared__ char lds[32768];   // As[128][128B] then Bs[128][128B]
  const int tid = threadIdx.x;
  const int l = tid & 63, w = tid >> 6;
  const int bm = blockIdx.x * 128, bn = blockIdx.y * 128;
  const int wm = w >> 1, wn = w & 1;
  f32x4 acc[4][4] = {};

  for (int k0 = 0; k0 < K; k0 += 64) {
    __syncthreads();   // previous tile's reads complete before overwrite
#pragma unroll
    for (int q = 0; q < 4; ++q) {
      int o = q * 4096 + tid * 16;          // linear LDS byte offset
      int r = o >> 7;                        // tile row
      int pc = (o >> 4) & 7;                 // LDS chunk (16B units)
      int gc = pc ^ (r & 7);                 // global chunk to land here
      const char* srcA = (const char*)A + ((size_t)(bm + r) * K + k0) * 2 + gc * 16;
      const char* srcB = (const char*)Bt + ((size_t)(bn + r) * K + k0) * 2 + gc * 16;
      __builtin_amdgcn_global_load_lds(
          (const __attribute__((address_space(1))) void*)srcA,
          (__attribute__((address_space(3))) void*)(lds + o), 16, 0, 0);
      __builtin_amdgcn_global_load_lds(
          (const __attribute__((address_space(1))) void*)srcB,
          (__attribute__((address_space(3))) void*)(lds + 16384 + o), 16, 0, 0);
    }
    __syncthreads();

#pragma unroll
    for (int kk = 0; kk < 64; kk += 32) {
      bf16x8 af[4], bf[4];
#pragma unroll
      for (int mi = 0; mi < 4; ++mi) {
        int r = wm * 64 + mi * 16 + (l & 15);
        int gc = (kk >> 3) + (l >> 4);
        af[mi] = *(const bf16x8*)(lds + r * 128 + ((gc ^ (r & 7)) << 4));
      }
#pragma unroll
      for (int ni = 0; ni < 4; ++ni) {
        int r = wn * 64 + ni * 16 + (l & 15);
        int gc = (kk >> 3) + (l >> 4);
        bf[ni] = *(const bf16x8*)(lds + 16384 + r * 128 + ((gc ^ (r & 7)) << 4));
      }
#pragma unroll
      for (int mi = 0; mi < 4; ++mi)
#pragma unroll
        for (int ni = 0; ni < 4; ++ni)
          acc[mi][ni] = __builtin_amdgcn_mfma_f32_16x16x32_bf16(af[mi], bf[ni],
                                                                acc[mi][ni], 0, 0, 0);
    }
  }

  // epilogue: C row = bm+wm*64+mi*16+(l>>4)*4+r, col = bn+wn*64+ni*16+(l&15)
#pragma unroll
  for (int mi = 0; mi < 4; ++mi) {
#pragma unroll
    for (int ni = 0; ni < 4; ++ni) {
      int row0 = bm + wm * 64 + mi * 16 + ((l >> 4) << 2);
      int col = bn + wn * 64 + ni * 16 + (l & 15);
      float bv = BIAS_RELU ? bias[col] : 0.f;
      f32x4 v = acc[mi][ni];
#pragma unroll
      for (int r = 0; r < 4; ++r) {
        float val = v[r];
        if (BIAS_RELU) val = fmaxf(val + bv, 0.f);
        if (OUT_BF16)
          ((unsigned short*)C)[(size_t)(row0 + r) * N + col] = f2bf(val);
        else
          ((float*)C)[(size_t)(row0 + r) * N + col] = val;
      }
    }
  }
}

// ---------------- launch ----------------
extern "C" void kernel_launch(void* const* d_in, const int* in_sizes, int n_in,
                              void* d_out, int out_size, void* d_ws, size_t ws_size,
                              hipStream_t stream) {
  const float* dm = (const float*)d_in[0];   // [4,1,64,64]
  const float* fm = (const float*)d_in[1];   // [4,256,64,64]
  const float* W1 = (const float*)d_in[2];   // [256,512]
  const float* b1 = (const float*)d_in[3];   // [512]
  const float* W2 = (const float*)d_in[4];   // [512,256]
  const float* b2 = (const float*)d_in[5];   // [256]
  float* out = (float*)d_out;                // [4,256,64,64]

  char* ws = (char*)d_ws;
  int*            tgt   = (int*)(ws + 0x000000);
  int*            deg   = (int*)(ws + 0x040000);
  float*          dinv  = (float*)(ws + 0x050000);
  int*            off   = (int*)(ws + 0x060000);
  int*            cur   = (int*)(ws + 0x080000);
  int*            srcs  = (int*)(ws + 0x0A0000);
  unsigned short* W1t   = (unsigned short*)(ws + 0x0F0000);   // [512][256] bf16
  unsigned short* W2t   = (unsigned short*)(ws + 0x130000);   // [256][512] bf16
  unsigned long long* skeys = (unsigned long long*)(ws + 0x170000);  // [4][4096] u64
  int*            rank  = (int*)(ws + 0x190000);              // [16384]
  float*          x     = (float*)(ws + 0x200000);            // [16384][256] f32
  unsigned short* px    = (unsigned short*)(ws + 0x1200000);  // [16384][256] bf16
  unsigned short* h1    = (unsigned short*)(ws + 0x1A00000);  // [16384][512] bf16
  float*          t2    = (float*)(ws + 0x2A00000);           // [16384][256] f32
  (void)ws_size; (void)in_sizes; (void)n_in; (void)out_size;

  init_deg_kernel<<<64, 256, 0, stream>>>(deg);
  sort_kernel<<<NB, 1024, 0, stream>>>(dm, skeys, rank);
  knn_select_kernel<<<N_NODES / 256, 256, 0, stream>>>(skeys, rank, tgt, deg);
  scan_kernel<<<1, 256, 0, stream>>>(deg, dinv, off, cur);
  fill_csr_kernel<<<NEDGE / 256, 256, 0, stream>>>(tgt, cur, srcs);

  // weights -> bf16 [N][K]
  transpose_cvt_bf16_kernel<<<dim3(512 / 32, 256 / 32), 256, 0, stream>>>(W1, W1t, 256, 512);
  transpose_cvt_bf16_kernel<<<dim3(256 / 32, 512 / 32), 256, 0, stream>>>(W2, W2t, 512, 256);

  // feature maps [B][256][4096] -> node-major [B*4096][256]
  transpose_kernel<<<dim3(4096 / 32, 256 / 32, NB), 256, 0, stream>>>(fm, x, 256, 4096);

  // layer 1: propagate x (256) -> bf16, then MFMA GEMM relu(.@W1+b1) -> bf16
  prop_kernel<true, false><<<N_NODES / 4, 256, 0, stream>>>(x, px, off, srcs, dinv, nullptr);
  gemm_bf16_kernel<true, true><<<dim3(128, 4), 256, 0, stream>>>(
      px, W1t, h1, b1, 16384, 512, 256);

  // layer 2: MFMA GEMM h1@W2 -> f32, then propagate + bias + relu (f32, into x buf)
  gemm_bf16_kernel<false, false><<<dim3(128, 2), 256, 0, stream>>>(
      h1, W2t, t2, nullptr, 16384, 256, 512);
  prop_kernel<false, true><<<N_NODES / 4, 256, 0, stream>>>(t2, x, off, srcs, dinv, b2);

  // node-major -> [B][256][4096]
  transpose_kernel<<<dim3(256 / 32, 4096 / 32, NB), 256, 0, stream>>>(x, out, 4096, 256);
}

// Round 7
// 130.775 us; speedup vs baseline: 2.0760x; 1.1508x over previous
//
#include <hip/hip_runtime.h>
#include <hip/hip_bf16.h>
#include <stdint.h>

// Problem constants (fixed by setup_inputs)
#define N_NODES 16384   // B*H*W
#define NPB     4096    // nodes per batch (H*W)
#define NB      4
#define KNN     4
#define NEDGE   (N_NODES * 5)   // 4 kNN + 1 self loop per node
#define WIN     12      // sorted-order window radius for exact 1-D kNN
#define NBUK    4096    // buckets per batch (uniform densities -> avg 1/bucket)

typedef short bf16x8 __attribute__((ext_vector_type(8)));
typedef float f32x4 __attribute__((ext_vector_type(4)));

__device__ __forceinline__ unsigned short f2bf(float f) {
  unsigned u = __float_as_uint(f);
  unsigned r = (u + 0x7fff + ((u >> 16) & 1)) >> 16;   // RNE
  return (unsigned short)r;
}
__device__ __forceinline__ float bf2f(unsigned short u) {
  return __uint_as_float(((unsigned)u) << 16);
}

// ---------------- S1: init (deg=1, bucket hist=0) ----------------
__global__ void init_kernel(int* __restrict__ deg, int* __restrict__ bhist) {
  int i = blockIdx.x * 256 + threadIdx.x;
  if (i < N_NODES) { deg[i] = 1; bhist[i] = 0; }
}

// ---------------- S2: bucket histogram ----------------
__global__ void hist_kernel(const float* __restrict__ dm, int* __restrict__ bhist) {
  int e = blockIdx.x * 256 + threadIdx.x;
  if (e >= N_NODES) return;
  int b = e >> 12;
  float v = dm[e];
  int bk = (int)(v * (float)NBUK); if (bk > NBUK - 1) bk = NBUK - 1;
  atomicAdd(&bhist[b * NBUK + bk], 1);
}

// ---------------- S3: exclusive scan of 16384 bucket counts (per-batch sums=4096,
// so batch b's global slots are exactly [b*4096,(b+1)*4096)) ----------------
__global__ void bscan_kernel(const int* __restrict__ bhist, int* __restrict__ bstart,
                             int* __restrict__ bcur) {
  __shared__ int part[256];
  int t = threadIdx.x;
  int base = t * 64;
  int s = 0;
  for (int i = 0; i < 64; ++i) s += bhist[base + i];
  part[t] = s;
  __syncthreads();
  if (t == 0) {
    int acc = 0;
    for (int i = 0; i < 256; ++i) { int v = part[i]; part[i] = acc; acc += v; }
  }
  __syncthreads();
  int acc = part[t];
  for (int i = 0; i < 64; ++i) {
    bstart[base + i] = acc;
    bcur[base + i] = acc;
    acc += bhist[base + i];
  }
  if (t == 255) bstart[N_NODES] = N_NODES;
}

// ---------------- S4: scatter keys into bucket slots (unordered within bucket) ---
__global__ void scatter_kernel(const float* __restrict__ dm, int* __restrict__ bcur,
                               unsigned long long* __restrict__ tmpkeys) {
  int e = blockIdx.x * 256 + threadIdx.x;
  if (e >= N_NODES) return;
  int b = e >> 12, li = e & (NPB - 1);
  float v = dm[e];
  int bk = (int)(v * (float)NBUK); if (bk > NBUK - 1) bk = NBUK - 1;
  int slot = atomicAdd(&bcur[b * NBUK + bk], 1);
  tmpkeys[slot] = (((unsigned long long)__float_as_uint(v)) << 32) | (unsigned)li;
}

// ---------------- S5: finalize — exact (value,idx) order within bucket ----------
// BUGFIX vs R6: rank must be the BATCH-LOCAL sorted position. Global slot base for
// batch b equals b*4096 (per-batch bucket counts sum to 4096), so subtract it.
__global__ void bfinal_kernel(const unsigned long long* __restrict__ tmpkeys,
                              const int* __restrict__ bstart,
                              unsigned long long* __restrict__ skeys,
                              int* __restrict__ rank) {
  int g = blockIdx.x * 256 + threadIdx.x;   // global bucket id
  if (g >= N_NODES) return;
  int s0 = bstart[g], s1 = bstart[g + 1];
  int cnt = s1 - s0;
  if (cnt <= 0) return;
  int batch_base = (g >> 12) << 12;   // batch*NPB == batch's global slot base
  if (cnt == 1) {
    unsigned long long k = tmpkeys[s0];
    skeys[s0] = k;
    rank[batch_base + (int)(k & 0xffffffffull)] = s0 - batch_base;
    return;
  }
  for (int i = s0; i < s1; ++i) {
    unsigned long long ki = tmpkeys[i];
    int r = 0;
    for (int j = s0; j < s1; ++j) r += (tmpkeys[j] < ki);
    skeys[s0 + r] = ki;
    rank[batch_base + (int)(ki & 0xffffffffull)] = (s0 + r) - batch_base;
  }
}

// ---------------- kNN select: exact top-5 by (dist,idx) within sorted window -----
__global__ void knn_select_kernel(const unsigned long long* __restrict__ skeys,
                                  const int* __restrict__ rank,
                                  int* __restrict__ tgt, int* __restrict__ deg) {
  int node = blockIdx.x * 256 + threadIdx.x;
  if (node >= N_NODES) return;
  int b = node >> 12;            // / NPB
  int p = rank[node];            // batch-local sorted position
  const unsigned long long* sk = skeys + b * NPB;
  float di = __uint_as_float((unsigned)(sk[p] >> 32));
  int lo = p - WIN; if (lo < 0) lo = 0;
  int hi = p + WIN; if (hi > NPB - 1) hi = NPB - 1;
  unsigned long long k0 = ~0ull, k1 = ~0ull, k2 = ~0ull, k3 = ~0ull, k4 = ~0ull;
  for (int q = lo; q <= hi; ++q) {
    unsigned long long key = sk[q];
    float v = __uint_as_float((unsigned)(key >> 32));
    float dist = fabsf(di - v);
    unsigned long long dk = (((unsigned long long)__float_as_uint(dist)) << 32) |
                            (key & 0xffffffffull);
    if (dk < k4) {
      if (dk < k0)      { k4 = k3; k3 = k2; k2 = k1; k1 = k0; k0 = dk; }
      else if (dk < k1) { k4 = k3; k3 = k2; k2 = k1; k1 = dk; }
      else if (dk < k2) { k4 = k3; k3 = k2; k2 = dk; }
      else if (dk < k3) { k4 = k3; k3 = dk; }
      else              { k4 = dk; }
    }
  }
  int base = b * NPB;
  int t0 = base + (int)(k1 & 0xffffffffull);
  int t1 = base + (int)(k2 & 0xffffffffull);
  int t2 = base + (int)(k3 & 0xffffffffull);
  int t3 = base + (int)(k4 & 0xffffffffull);
  tgt[node * KNN + 0] = t0; atomicAdd(&deg[t0], 1);
  tgt[node * KNN + 1] = t1; atomicAdd(&deg[t1], 1);
  tgt[node * KNN + 2] = t2; atomicAdd(&deg[t2], 1);
  tgt[node * KNN + 3] = t3; atomicAdd(&deg[t3], 1);
}

// ---------------- dinv + exclusive scan of deg (single block) ----------------
__global__ void scan_kernel(const int* __restrict__ deg, float* __restrict__ dinv,
                            int* __restrict__ off, int* __restrict__ cur) {
  __shared__ int part[256];
  int t = threadIdx.x;
  int base = t * 64;
  int s = 0;
  for (int i = 0; i < 64; ++i) s += deg[base + i];
  part[t] = s;
  __syncthreads();
  if (t == 0) {
    int acc = 0;
    for (int i = 0; i < 256; ++i) { int v = part[i]; part[i] = acc; acc += v; }
  }
  __syncthreads();
  int acc = part[t];
  for (int i = 0; i < 64; ++i) {
    int dg = deg[base + i];
    off[base + i] = acc;
    cur[base + i] = acc;
    dinv[base + i] = rsqrtf((float)dg);
    acc += dg;
  }
  if (t == 255) off[N_NODES] = acc;  // == NEDGE
}

// ---------------- CSR fill (incoming edges per node) ----------------
__global__ void fill_csr_kernel(const int* __restrict__ tgt, int* __restrict__ cur,
                                int* __restrict__ srcs) {
  int e = blockIdx.x * 256 + threadIdx.x;
  if (e >= NEDGE) return;
  int j = e / 5, q = e - j * 5;
  int target = (q < KNN) ? tgt[j * KNN + q] : j;   // q==4 -> self loop
  int pos = atomicAdd(&cur[target], 1);
  srcs[pos] = j;
}

// ---------------- fp32 batched transpose: [B][Rin][Cin] -> [B][Cin][Rin] --------
__global__ void transpose_kernel(const float* __restrict__ in, float* __restrict__ out,
                                 int Rin, int Cin) {
  __shared__ float tile[32][33];
  int c0 = blockIdx.x * 32, r0 = blockIdx.y * 32, b = blockIdx.z;
  int tx = threadIdx.x & 31, ty = threadIdx.x >> 5;   // 32x8
  const float* ip = in + ((size_t)b * Rin + r0) * Cin + c0;
#pragma unroll
  for (int i = 0; i < 32; i += 8) tile[ty + i][tx] = ip[(size_t)(ty + i) * Cin + tx];
  __syncthreads();
  float* op = out + ((size_t)b * Cin + c0) * Rin + r0;
#pragma unroll
  for (int i = 0; i < 32; i += 8) op[(size_t)(ty + i) * Rin + tx] = tile[tx][ty + i];
}

// ---------------- batched transpose + cvt bf16: [B][Rin][Cin]f32 -> [B][Cin][Rin]bf16
__global__ void transpose_cvt_bf16_kernel(const float* __restrict__ in,
                                          unsigned short* __restrict__ out,
                                          int Rin, int Cin) {
  __shared__ float tile[32][33];
  int c0 = blockIdx.x * 32, r0 = blockIdx.y * 32, b = blockIdx.z;
  int tx = threadIdx.x & 31, ty = threadIdx.x >> 5;
  const float* ip = in + ((size_t)b * Rin + r0) * Cin + c0;
#pragma unroll
  for (int i = 0; i < 32; i += 8) tile[ty + i][tx] = ip[(size_t)(ty + i) * Cin + tx];
  __syncthreads();
  unsigned short* op = out + ((size_t)b * Cin + c0) * Rin + r0;
#pragma unroll
  for (int i = 0; i < 32; i += 8) op[(size_t)(ty + i) * Rin + tx] = f2bf(tile[tx][ty + i]);
}

// ---------------- graph propagate: out[i,:] = dinv[i]*sum_j dinv[j]*in[j,:] ------
// 4 nodes per block; lane handles 4 channels.  C = 256 fixed.
template <bool IN_BF16, bool OUT_BF16, bool BIAS_RELU>
__global__ void prop_kernel(const void* __restrict__ in, void* __restrict__ out,
                            const int* __restrict__ off, const int* __restrict__ srcs,
                            const float* __restrict__ dinv, const float* __restrict__ bias) {
  int i = blockIdx.x * 4 + (threadIdx.x >> 6);
  int l = threadIdx.x & 63;
  int e0 = off[i], e1 = off[i + 1];
  float ax = 0.f, ay = 0.f, az = 0.f, aw = 0.f;
  for (int e = e0; e < e1; ++e) {
    int j = srcs[e];
    float dj = dinv[j];
    float vx, vy, vz, vw;
    if (IN_BF16) {
      ushort4 u = *(const ushort4*)((const unsigned short*)in + (size_t)j * 256 + l * 4);
      vx = bf2f(u.x); vy = bf2f(u.y); vz = bf2f(u.z); vw = bf2f(u.w);
    } else {
      float4 v = *(const float4*)((const float*)in + (size_t)j * 256 + l * 4);
      vx = v.x; vy = v.y; vz = v.z; vw = v.w;
    }
    ax = fmaf(dj, vx, ax); ay = fmaf(dj, vy, ay);
    az = fmaf(dj, vz, az); aw = fmaf(dj, vw, aw);
  }
  float di = dinv[i];
  ax *= di; ay *= di; az *= di; aw *= di;
  if (BIAS_RELU) {
    ax = fmaxf(ax + bias[l * 4 + 0], 0.f);
    ay = fmaxf(ay + bias[l * 4 + 1], 0.f);
    az = fmaxf(az + bias[l * 4 + 2], 0.f);
    aw = fmaxf(aw + bias[l * 4 + 3], 0.f);
  }
  if (OUT_BF16) {
    ushort4 o;
    o.x = f2bf(ax); o.y = f2bf(ay); o.z = f2bf(az); o.w = f2bf(aw);
    *(ushort4*)((unsigned short*)out + (size_t)i * 256 + l * 4) = o;
  } else {
    float4 o = make_float4(ax, ay, az, aw);
    *(float4*)((float*)out + (size_t)i * 256 + l * 4) = o;
  }
}

// ---------------- bf16 MFMA GEMM: C[M,N] = A[M,K] @ Bt[N,K]^T (+bias, relu) -----
// 128x128 tile, BK=64, 4 waves (2x2 of 64x64), global_load_lds width 16,
// XOR-swizzled LDS (chunk ^= row&7) applied on the GLOBAL source (rule #21).
template <bool BIAS_RELU, bool OUT_BF16>
__global__ __launch_bounds__(256)
void gemm_bf16_kernel(const unsigned short* __restrict__ A,   // [M][K] bf16
                      const unsigned short* __restrict__ Bt,  // [N][K] bf16
                      void* __restrict__ C, const float* __restrict__ bias,
                      int M, int N, int K) {
  __shared__ char lds[32768];   // As[128][128B] then Bs[128][128B]
  const int tid = threadIdx.x;
  const int l = tid & 63, w = tid >> 6;
  const int bm = blockIdx.x * 128, bn = blockIdx.y * 128;
  const int wm = w >> 1, wn = w & 1;
  f32x4 acc[4][4] = {};

  for (int k0 = 0; k0 < K; k0 += 64) {
    __syncthreads();   // previous tile's reads complete before overwrite
#pragma unroll
    for (int q = 0; q < 4; ++q) {
      int o = q * 4096 + tid * 16;          // linear LDS byte offset
      int r = o >> 7;                        // tile row
      int pc = (o >> 4) & 7;                 // LDS chunk (16B units)
      int gc = pc ^ (r & 7);                 // global chunk to land here
      const char* srcA = (const char*)A + ((size_t)(bm + r) * K + k0) * 2 + gc * 16;
      const char* srcB = (const char*)Bt + ((size_t)(bn + r) * K + k0) * 2 + gc * 16;
      __builtin_amdgcn_global_load_lds(
          (const __attribute__((address_space(1))) void*)srcA,
          (__attribute__((address_space(3))) void*)(lds + o), 16, 0, 0);
      __builtin_amdgcn_global_load_lds(
          (const __attribute__((address_space(1))) void*)srcB,
          (__attribute__((address_space(3))) void*)(lds + 16384 + o), 16, 0, 0);
    }
    __syncthreads();

#pragma unroll
    for (int kk = 0; kk < 64; kk += 32) {
      bf16x8 af[4], bf[4];
#pragma unroll
      for (int mi = 0; mi < 4; ++mi) {
        int r = wm * 64 + mi * 16 + (l & 15);
        int gc = (kk >> 3) + (l >> 4);
        af[mi] = *(const bf16x8*)(lds + r * 128 + ((gc ^ (r & 7)) << 4));
      }
#pragma unroll
      for (int ni = 0; ni < 4; ++ni) {
        int r = wn * 64 + ni * 16 + (l & 15);
        int gc = (kk >> 3) + (l >> 4);
        bf[ni] = *(const bf16x8*)(lds + 16384 + r * 128 + ((gc ^ (r & 7)) << 4));
      }
#pragma unroll
      for (int mi = 0; mi < 4; ++mi)
#pragma unroll
        for (int ni = 0; ni < 4; ++ni)
          acc[mi][ni] = __builtin_amdgcn_mfma_f32_16x16x32_bf16(af[mi], bf[ni],
                                                                acc[mi][ni], 0, 0, 0);
    }
  }

  // epilogue: C row = bm+wm*64+mi*16+(l>>4)*4+r, col = bn+wn*64+ni*16+(l&15)
#pragma unroll
  for (int mi = 0; mi < 4; ++mi) {
#pragma unroll
    for (int ni = 0; ni < 4; ++ni) {
      int row0 = bm + wm * 64 + mi * 16 + ((l >> 4) << 2);
      int col = bn + wn * 64 + ni * 16 + (l & 15);
      float bv = BIAS_RELU ? bias[col] : 0.f;
      f32x4 v = acc[mi][ni];
#pragma unroll
      for (int r = 0; r < 4; ++r) {
        float val = v[r];
        if (BIAS_RELU) val = fmaxf(val + bv, 0.f);
        if (OUT_BF16)
          ((unsigned short*)C)[(size_t)(row0 + r) * N + col] = f2bf(val);
        else
          ((float*)C)[(size_t)(row0 + r) * N + col] = val;
      }
    }
  }
}

// ---------------- launch ----------------
extern "C" void kernel_launch(void* const* d_in, const int* in_sizes, int n_in,
                              void* d_out, int out_size, void* d_ws, size_t ws_size,
                              hipStream_t stream) {
  const float* dm = (const float*)d_in[0];   // [4,1,64,64]
  const float* fm = (const float*)d_in[1];   // [4,256,64,64]
  const float* W1 = (const float*)d_in[2];   // [256,512]
  const float* b1 = (const float*)d_in[3];   // [512]
  const float* W2 = (const float*)d_in[4];   // [512,256]
  const float* b2 = (const float*)d_in[5];   // [256]
  float* out = (float*)d_out;                // [4,256,64,64]

  char* ws = (char*)d_ws;
  int*            tgt   = (int*)(ws + 0x000000);              // 256KB
  int*            deg   = (int*)(ws + 0x040000);              // 64KB
  float*          dinv  = (float*)(ws + 0x050000);            // 64KB
  int*            off   = (int*)(ws + 0x060000);              // 64KB+4
  int*            cur   = (int*)(ws + 0x080000);              // 64KB+4
  int*            srcs  = (int*)(ws + 0x0A0000);              // 320KB
  unsigned short* W1t   = (unsigned short*)(ws + 0x0F0000);   // [512][256] bf16
  unsigned short* W2t   = (unsigned short*)(ws + 0x130000);   // [256][512] bf16
  unsigned long long* skeys = (unsigned long long*)(ws + 0x170000);  // 128KB
  int*            rank  = (int*)(ws + 0x190000);              // 64KB
  int*            bhist = (int*)(ws + 0x1A0000);              // 64KB
  int*            bstart= (int*)(ws + 0x1B0000);              // 64KB+4
  int*            bcur  = (int*)(ws + 0x1D0000);              // 64KB
  unsigned long long* tmpkeys = (unsigned long long*)(ws + 0x1E0000); // 128KB
  unsigned short* px0   = (unsigned short*)(ws + 0x0200000);  // [16384][256] bf16
  unsigned short* px    = (unsigned short*)(ws + 0x0A00000);  // [16384][256] bf16
  unsigned short* h1    = (unsigned short*)(ws + 0x1200000);  // [16384][512] bf16
  float*          t2    = (float*)(ws + 0x2200000);           // [16384][256] f32
  float*          xout  = (float*)(ws + 0x3200000);           // [16384][256] f32
  (void)ws_size; (void)in_sizes; (void)n_in; (void)out_size;

  // ---- graph build: counting sort by density, then windowed exact kNN ----
  init_kernel<<<64, 256, 0, stream>>>(deg, bhist);
  hist_kernel<<<64, 256, 0, stream>>>(dm, bhist);
  bscan_kernel<<<1, 256, 0, stream>>>(bhist, bstart, bcur);
  scatter_kernel<<<64, 256, 0, stream>>>(dm, bcur, tmpkeys);
  bfinal_kernel<<<64, 256, 0, stream>>>(tmpkeys, bstart, skeys, rank);
  knn_select_kernel<<<64, 256, 0, stream>>>(skeys, rank, tgt, deg);
  scan_kernel<<<1, 256, 0, stream>>>(deg, dinv, off, cur);
  fill_csr_kernel<<<NEDGE / 256, 256, 0, stream>>>(tgt, cur, srcs);

  // weights -> bf16 [N][K]
  transpose_cvt_bf16_kernel<<<dim3(512 / 32, 256 / 32, 1), 256, 0, stream>>>(W1, W1t, 256, 512);
  transpose_cvt_bf16_kernel<<<dim3(256 / 32, 512 / 32, 1), 256, 0, stream>>>(W2, W2t, 512, 256);

  // feature maps [B][256][4096] f32 -> node-major [B*4096][256] bf16
  transpose_cvt_bf16_kernel<<<dim3(4096 / 32, 256 / 32, NB), 256, 0, stream>>>(fm, px0, 256, 4096);

  // layer 1: propagate (bf16 in -> bf16 out), then MFMA GEMM relu(.@W1+b1) -> bf16
  prop_kernel<true, true, false><<<N_NODES / 4, 256, 0, stream>>>(
      px0, px, off, srcs, dinv, nullptr);
  gemm_bf16_kernel<true, true><<<dim3(128, 4), 256, 0, stream>>>(
      px, W1t, h1, b1, 16384, 512, 256);

  // layer 2: MFMA GEMM h1@W2 -> f32, then propagate + bias + relu (f32)
  gemm_bf16_kernel<false, false><<<dim3(128, 2), 256, 0, stream>>>(
      h1, W2t, t2, nullptr, 16384, 256, 512);
  prop_kernel<false, false, true><<<N_NODES / 4, 256, 0, stream>>>(
      t2, xout, off, srcs, dinv, b2);

  // node-major -> [B][256][4096]
  transpose_kernel<<<dim3(256 / 32, 4096 / 32, NB), 256, 0, stream>>>(xout, out, 4096, 256);
}